// Round 12
// baseline (78.253 us; speedup 1.0000x reference)
//
#include <hip/hip_runtime.h>
#include <hip/hip_bf16.h>

typedef __attribute__((ext_vector_type(8))) short bf16x8;
typedef __attribute__((ext_vector_type(4))) float f32x4;

constexpr int NB = 16, CIN = 256, COUT = 256, TDIM = 4096, KS = 3, PADV = 1;
constexpr int TT = 128;            // t per block
constexpr int BK = 64;             // K-step (64 channels of one tap)
constexpr int NSTEP = 12;          // 4 c-blocks x 3 taps

typedef __attribute__((address_space(1))) const unsigned int gu32;
typedef __attribute__((address_space(3))) unsigned int lu32;

static __device__ __forceinline__ ushort f2bf(float f) {
    union { __hip_bfloat16 h; ushort u; } cv;
    cv.h = __float2bfloat16(f);
    return cv.u;
}
static __device__ __forceinline__ float bf2f(ushort u) {
    union { unsigned int u32; float f; } cv;
    cv.u32 = ((unsigned int)u) << 16;
    return cv.f;
}

// Step s = cb*3 + k covers channels [cb*64, cb*64+64) of tap k. Per-step LDS
// image PRE-swizzled so a linear global_load_lds lands such that byte
// (o*128 + oc*16)^((o&7)<<4) holds W[o][tap k][c0 + oc*8 .. +8].
__global__ __launch_bounds__(256) void prepack_w(const float* __restrict__ w,
                                                 __hip_bfloat16* __restrict__ wp) {
    int idx = blockIdx.x * 256 + threadIdx.x;      // NSTEP*COUT*BK = 196608
    if (idx >= NSTEP * COUT * BK) return;
    int e  = idx & 7;
    int j  = (idx >> 3) & 7;
    int o  = (idx >> 6) & (COUT - 1);
    int s  = idx >> 14;                            // 0..11
    int k  = s % 3;
    int c  = (s / 3) * 64 + ((j ^ (o & 7)) << 3) + e;
    wp[idx] = __float2bfloat16(w[(o * CIN + c) * KS + k]);
}

// x (B,C,T) f32  ->  xT (B,T,C) bf16.  64c x 64t tile per block via LDS.
__global__ __launch_bounds__(256) void transpose_x(const float* __restrict__ x,
                                                   ushort* __restrict__ xT) {
    __shared__ ushort tile[64][72];    // [t][c], pad 8 to break pow2 stride
    const int b  = blockIdx.z;
    const int c0 = blockIdx.y * 64;
    const int t0 = blockIdx.x * 64;
    const int tid = threadIdx.x;
    {
        const int c  = tid >> 2;             // 0..63
        const int tq = (tid & 3) << 4;       // 0,16,32,48
        const float* src = x + ((size_t)(b * CIN + c0 + c)) * TDIM + t0 + tq;
        #pragma unroll
        for (int i = 0; i < 4; ++i) {
            float4 f = *(const float4*)(src + 4 * i);
            tile[tq + 4 * i + 0][c] = f2bf(f.x);
            tile[tq + 4 * i + 1][c] = f2bf(f.y);
            tile[tq + 4 * i + 2][c] = f2bf(f.z);
            tile[tq + 4 * i + 3][c] = f2bf(f.w);
        }
    }
    __syncthreads();
    {
        const int t = tid >> 2;              // 0..63
        const int q = tid & 3;               // 16-channel chunk
        const uint4* lp = (const uint4*)&tile[t][q * 16];   // 16B aligned
        uint4 v0 = lp[0], v1 = lp[1];
        uint4* dst = (uint4*)(xT + ((size_t)b * TDIM + t0 + t) * CIN + c0 + q * 16);
        dst[0] = v0;
        dst[1] = v1;
    }
}

// ---- main kernel: dbuf LDS + single barrier/step + counted vmcnt ----
__global__ __launch_bounds__(512, 2) void deform_mfma_xt(
    const ushort* __restrict__ xT,            // (NB, TDIM, CIN) bf16
    const float* __restrict__ off,            // (NB, 2*KS, TDIM, 1)
    const __hip_bfloat16* __restrict__ wp,    // swizzled pack, 384 KB
    const float* __restrict__ bias,           // (COUT)
    float* __restrict__ out)                  // (NB, COUT, TDIM)
{
    __shared__ ushort w_s[2][COUT * BK];    // 2 x 32 KB swizzled W images
    __shared__ ushort v_s[2][TT * BK];      // 2 x 16 KB swizzled V tiles
    __shared__ int4   sP[KS][TT];           // {base, waf, wbf, -}  6 KB

    const int tid = threadIdx.x;

    // XCD-chunked bijective swizzle: XCD q (= bid%8) owns batches {2q, 2q+1}.
    const int bid  = blockIdx.x;           // 0..511
    const int q    = bid & 7;
    const int r    = bid >> 3;             // 0..63
    const int b    = 2 * q + (r >> 5);
    const int tt0  = (r & 31) * TT;

    // ---- Phase A: per-(k,t) base row + pair-ordered f32 weights ----
    if (tid < KS * TT) {
        int k = tid >> 7, j = tid & (TT - 1);
        int t = tt0 + j;
        float dyr = off[((b * 2 * KS + 2 * k) * TDIM) + t];
        float dxr = off[((b * 2 * KS + 2 * k + 1) * TDIM) + t];
        float dyk = dyr - (float)(k - PADV);
        float py  = (float)(t - PADV + k) + dyk;
        float i0f = floorf(py);
        float fr  = py - i0f;
        int i0 = (int)i0f, i1 = i0 + 1;
        float wx = fmaxf(0.0f, 1.0f - fabsf(dxr));
        float w0 = (1.0f - fr) * wx * ((i0 >= 0 && i0 < TDIM) ? 1.0f : 0.0f);
        float w1 = fr * wx * ((i1 >= 0 && i1 < TDIM) ? 1.0f : 0.0f);
        int base = min(max(i0, 0), TDIM - 2);
        bool iA = (i0 == base);
        float wa = iA ? w0 : ((i0 + 1 == base) ? w1 : 0.0f);
        float wb = iA ? w1 : ((i0 == base + 1) ? w0 : 0.0f);
        int4 p;
        p.x = base;
        p.y = __float_as_int(wa);
        p.z = __float_as_int(wb);
        p.w = 0;
        sP[k][tid & (TT - 1)] = p;
    }

    const int wid    = tid >> 6;
    const int lane   = tid & 63;
    const int o_base = (wid >> 1) * 64;
    const int t_base = (wid & 1) * 64;
    const int lr     = lane & 15;
    const int lg     = lane >> 4;

    // V-phase mapping: 8 lanes per t -> coalesced 128B row segments
    const int tg   = tid >> 3;             // 0..63
    const int slot = tid & 7;              // 8-channel slot
    const int t0l  = tg;
    const int t1l  = tg + 64;
    const int voffA = (t0l * 128 + slot * 16) ^ ((t0l & 7) << 4);
    const int voffB = (t1l * 128 + slot * 16) ^ ((t1l & 7) << 4);

    f32x4 acc[4][4];
    #pragma unroll
    for (int i = 0; i < 4; ++i)
        #pragma unroll
        for (int j = 0; j < 4; ++j) acc[i][j] = (f32x4)0.0f;

    const ushort* xTb = xT + (size_t)b * TDIM * CIN;

#define STAGE_W(SIDX, BUF) do {                                                     \
    const char* gb_ = (const char*)wp + (size_t)(SIDX) * 32768 + wid * 4096 + lane * 16; \
    char* lb_ = (char*)w_s[BUF] + wid * 4096;                                       \
    __builtin_amdgcn_global_load_lds((gu32*)(gb_),        (lu32*)(lb_),        16, 0, 0); \
    __builtin_amdgcn_global_load_lds((gu32*)(gb_ + 1024), (lu32*)(lb_ + 1024), 16, 0, 0); \
    __builtin_amdgcn_global_load_lds((gu32*)(gb_ + 2048), (lu32*)(lb_ + 2048), 16, 0, 0); \
    __builtin_amdgcn_global_load_lds((gu32*)(gb_ + 3072), (lu32*)(lb_ + 3072), 16, 0, 0); \
} while (0)

#define GATHER(SN) do {                                                             \
    int kn_  = (SN) % 3;                                                            \
    int cbn_ = ((SN) / 3) * 64;                                                     \
    int4 e0_ = sP[kn_][t0l];                                                        \
    int4 e1_ = sP[kn_][t1l];                                                        \
    const ushort* rA_ = xTb + (size_t)e0_.x * CIN + cbn_ + slot * 8;                \
    const ushort* rB_ = xTb + (size_t)e1_.x * CIN + cbn_ + slot * 8;                \
    ga0 = *(const bf16x8*)rA_;                                                      \
    ga1 = *(const bf16x8*)(rA_ + CIN);                                              \
    gb0 = *(const bf16x8*)rB_;                                                      \
    gb1 = *(const bf16x8*)(rB_ + CIN);                                              \
    wa0 = __int_as_float(e0_.y); wb0 = __int_as_float(e0_.z);                       \
    wa1 = __int_as_float(e1_.y); wb1 = __int_as_float(e1_.z);                       \
} while (0)

#define INTERP() do {                                                               \
    _Pragma("unroll")                                                               \
    for (int i_ = 0; i_ < 8; ++i_) {                                                \
        pk0[i_] = (short)f2bf(bf2f((ushort)ga0[i_]) * wa0 + bf2f((ushort)ga1[i_]) * wb0); \
        pk1[i_] = (short)f2bf(bf2f((ushort)gb0[i_]) * wa1 + bf2f((ushort)gb1[i_]) * wb1); \
    }                                                                               \
} while (0)

#define MFMA_PHASE(P) do {                                                          \
    _Pragma("unroll")                                                               \
    for (int kb = 0; kb < 2; ++kb) {                                                \
        const int kk = kb * 32 + lg * 8;                                            \
        bf16x8 bfr[4];                                                              \
        _Pragma("unroll")                                                           \
        for (int nf = 0; nf < 4; ++nf) {                                            \
            int tc = t_base + nf * 16 + lr;                                         \
            int byte = (tc * 128 + kk * 2) ^ ((tc & 7) << 4);                       \
            bfr[nf] = *(const bf16x8*)((const char*)v_s[P] + byte);                 \
        }                                                                           \
        _Pragma("unroll")                                                           \
        for (int mf = 0; mf < 4; ++mf) {                                            \
            int o = o_base + mf * 16 + lr;                                          \
            int byte = (o * 128 + kk * 2) ^ ((o & 7) << 4);                         \
            bf16x8 af = *(const bf16x8*)((const char*)w_s[P] + byte);               \
            _Pragma("unroll")                                                       \
            for (int nf = 0; nf < 4; ++nf)                                          \
                acc[mf][nf] = __builtin_amdgcn_mfma_f32_16x16x32_bf16(              \
                    af, bfr[nf], acc[mf][nf], 0, 0, 0);                             \
        }                                                                           \
    }                                                                               \
} while (0)

    __syncthreads();   // sP visible (full drain once)

    // ---- Prologue: stage step 0 ----
    bf16x8 ga0, ga1, gb0, gb1, pk0, pk1;
    float wa0, wb0, wa1, wb1;
    STAGE_W(0, 0);          // W-DMA(0) -> w_s[0]
    GATHER(0);
    INTERP();               // compiler's vmcnt here also drains W-DMA(0)

    // ---- Main loop s = 0..10: single barrier, counted vmcnt ----
    #pragma unroll 1
    for (int s = 0; s < NSTEP - 1; ++s) {
        const int p = s & 1;
        // commit V(s) from regs
        *(bf16x8*)((char*)v_s[p] + voffA) = pk0;
        *(bf16x8*)((char*)v_s[p] + voffB) = pk1;
        // prefetch gathers for s+1 (4 newest vmem ops)
        GATHER(s + 1);
        __builtin_amdgcn_sched_barrier(0);
        // drain W-DMA(s) (older) + own LDS ops; leave the 4 gathers in flight
        asm volatile("s_waitcnt vmcnt(4) lgkmcnt(0)" ::: "memory");
        __builtin_amdgcn_sched_barrier(0);
        __builtin_amdgcn_s_barrier();       // B_s: v_s[p], w_s[p] valid for all
        __builtin_amdgcn_sched_barrier(0);
        // stage next W into the buffer MFMA(s) does NOT read (readers of it
        // were MFMA(s-1), all retired at B_s)
        STAGE_W(s + 1, p ^ 1);
        MFMA_PHASE(p);
        // finish V(s+1): compiler emits exact vmcnt for the gather regs
        INTERP();
    }

    // ---- Peeled last step (s = 11, p = 1): no prefetch, full drain ----
    {
        *(bf16x8*)((char*)v_s[1] + voffA) = pk0;
        *(bf16x8*)((char*)v_s[1] + voffB) = pk1;
        __builtin_amdgcn_sched_barrier(0);
        asm volatile("s_waitcnt vmcnt(0) lgkmcnt(0)" ::: "memory");
        __builtin_amdgcn_sched_barrier(0);
        __builtin_amdgcn_s_barrier();
        __builtin_amdgcn_sched_barrier(0);
        MFMA_PHASE(1);
    }

    // ---- Epilogue: D col = lane&15 (t), row = (lane>>4)*4 + reg (o) ----
    #pragma unroll
    for (int mf = 0; mf < 4; ++mf) {
        #pragma unroll
        for (int r2 = 0; r2 < 4; ++r2) {
            int o = o_base + mf * 16 + lg * 4 + r2;
            float bv = bias[o];
            float* orow = out + (size_t)(b * COUT + o) * TDIM + tt0 + t_base;
            #pragma unroll
            for (int nf = 0; nf < 4; ++nf)
                __builtin_nontemporal_store(acc[mf][nf][r2] + bv, &orow[nf * 16 + lr]);
        }
    }
#undef STAGE_W
#undef GATHER
#undef INTERP
#undef MFMA_PHASE
}

// ---- fallback (proven 81us R6 kernel): scalar gathers from x ----
__global__ __launch_bounds__(512, 4) void deform_mfma_gather(
    const float* __restrict__ x,
    const float* __restrict__ off,
    const __hip_bfloat16* __restrict__ wp,
    const float* __restrict__ bias,
    float* __restrict__ out)
{
    __shared__ ushort w_s[COUT * BK];
    __shared__ ushort v_s[TT * BK];
    __shared__ int4   sP[KS][TT];

    const int tid = threadIdx.x;
    const int bid  = blockIdx.x;
    const int q    = bid & 7;
    const int r    = bid >> 3;
    const int b    = 2 * q + (r >> 5);
    const int tt0  = (r & 31) * TT;

    if (tid < KS * TT) {
        int k = tid >> 7, j = tid & (TT - 1);
        int t = tt0 + j;
        float dyr = off[((b * 2 * KS + 2 * k) * TDIM) + t];
        float dxr = off[((b * 2 * KS + 2 * k + 1) * TDIM) + t];
        float py  = (float)(t - PADV + k) + dyr - (float)(k - PADV);
        float i0f = floorf(py);
        float fr  = py - i0f;
        int i0 = (int)i0f, i1 = i0 + 1;
        float wx = fmaxf(0.0f, 1.0f - fabsf(dxr));
        float w0 = (1.0f - fr) * wx * ((i0 >= 0 && i0 < TDIM) ? 1.0f : 0.0f);
        float w1 = fr * wx * ((i1 >= 0 && i1 < TDIM) ? 1.0f : 0.0f);
        int4 p;
        p.x = min(max(i0, 0), TDIM - 1);
        p.y = min(max(i1, 0), TDIM - 1);
        p.z = __float_as_int(w0);
        p.w = __float_as_int(w1);
        sP[k][j] = p;
    }

    const int wid    = tid >> 6;
    const int lane   = tid & 63;
    const int o_base = (wid >> 1) * 64;
    const int t_base = (wid & 1) * 64;
    const int lr     = lane & 15;
    const int lg     = lane >> 4;

    f32x4 acc[4][4];
    #pragma unroll
    for (int i = 0; i < 4; ++i)
        #pragma unroll
        for (int j = 0; j < 4; ++j) acc[i][j] = (f32x4)0.0f;

    const float* xb = x + (size_t)b * CIN * TDIM;

    for (int cb = 0; cb < 4; ++cb) {
      for (int k = 0; k < 3; ++k) {
        const int s_idx = cb * 3 + k;
        const int c0    = cb * 64;
        __syncthreads();
        {
            const char* gbase = (const char*)wp + (size_t)s_idx * 32768 + wid * 4096 + lane * 16;
            char* lbase = (char*)w_s + wid * 4096;
            #pragma unroll
            for (int i = 0; i < 4; ++i)
                __builtin_amdgcn_global_load_lds((gu32*)(gbase + i * 1024),
                                                 (lu32*)(lbase + i * 1024), 16, 0, 0);
        }
        {
            const int coct0 = tid >> 7;
            const int t     = tid & (TT - 1);
            int4 p = sP[k][t];
            const float* xr0 = xb + (size_t)(c0 + coct0 * 8) * TDIM;
            const float* xr1 = xr0 + (size_t)32 * TDIM;
            float g0[16], g1[16];
            #pragma unroll
            for (int i = 0; i < 8; ++i) {
                g0[2 * i]     = xr0[p.x];
                g0[2 * i + 1] = xr0[p.y];
                xr0 += TDIM;
            }
            #pragma unroll
            for (int i = 0; i < 8; ++i) {
                g1[2 * i]     = xr1[p.x];
                g1[2 * i + 1] = xr1[p.y];
                xr1 += TDIM;
            }
            float w0 = __int_as_float(p.z), w1 = __int_as_float(p.w);
            bf16x8 pk0, pk1;
            #pragma unroll
            for (int i = 0; i < 8; ++i) {
                pk0[i] = (short)f2bf(g0[2 * i] * w0 + g0[2 * i + 1] * w1);
                pk1[i] = (short)f2bf(g1[2 * i] * w0 + g1[2 * i + 1] * w1);
            }
            int row = t * (BK * 2);
            int swz = (t & 7) << 4;
            *(bf16x8*)((char*)v_s + ((row + coct0 * 16) ^ swz))       = pk0;
            *(bf16x8*)((char*)v_s + ((row + (coct0 + 4) * 16) ^ swz)) = pk1;
        }
        __syncthreads();
        #pragma unroll
        for (int kb = 0; kb < 2; ++kb) {
            const int kk = kb * 32 + lg * 8;
            bf16x8 bfr[4];
            #pragma unroll
            for (int nf = 0; nf < 4; ++nf) {
                int tc = t_base + nf * 16 + lr;
                int byte = (tc * (BK * 2) + kk * 2) ^ ((tc & 7) << 4);
                bfr[nf] = *(const bf16x8*)((const char*)v_s + byte);
            }
            #pragma unroll
            for (int mf = 0; mf < 4; ++mf) {
                int o  = o_base + mf * 16 + lr;
                int byte = (o * (BK * 2) + kk * 2) ^ ((o & 7) << 4);
                bf16x8 af = *(const bf16x8*)((const char*)w_s + byte);
                #pragma unroll
                for (int nf = 0; nf < 4; ++nf)
                    acc[mf][nf] = __builtin_amdgcn_mfma_f32_16x16x32_bf16(
                        af, bfr[nf], acc[mf][nf], 0, 0, 0);
            }
        }
      }
    }

    #pragma unroll
    for (int mf = 0; mf < 4; ++mf) {
        #pragma unroll
        for (int r2 = 0; r2 < 4; ++r2) {
            int o = o_base + mf * 16 + lg * 4 + r2;
            float bv = bias[o];
            float* orow = out + (size_t)(b * COUT + o) * TDIM + tt0 + t_base;
            #pragma unroll
            for (int nf = 0; nf < 4; ++nf)
                orow[nf * 16 + lr] = acc[mf][nf][r2] + bv;
        }
    }
}

extern "C" void kernel_launch(void* const* d_in, const int* in_sizes, int n_in,
                              void* d_out, int out_size, void* d_ws, size_t ws_size,
                              hipStream_t stream) {
    const float* x    = (const float*)d_in[0];
    const float* off  = (const float*)d_in[1];
    const float* w    = (const float*)d_in[2];
    const float* bias = (const float*)d_in[3];
    float* out = (float*)d_out;
    __hip_bfloat16* wp = (__hip_bfloat16*)d_ws;   // 384 KB swizzled pack

    prepack_w<<<dim3((NSTEP * COUT * BK + 255) / 256), dim3(256), 0, stream>>>(w, wp);

    const size_t xt_off  = 512 * 1024;
    const size_t xt_need = xt_off + (size_t)NB * TDIM * CIN * sizeof(ushort);

    if (ws_size >= xt_need) {
        ushort* xT = (ushort*)((char*)d_ws + xt_off);
        transpose_x<<<dim3(TDIM / 64, CIN / 64, NB), dim3(256), 0, stream>>>(x, xT);
        deform_mfma_xt<<<dim3(512), dim3(512), 0, stream>>>(xT, off, wp, bias, out);
    } else {
        deform_mfma_gather<<<dim3(512), dim3(512), 0, stream>>>(x, off, wp, bias, out);
    }
}

// Round 14
// 68.790 us; speedup vs baseline: 1.1376x; 1.1376x over previous
//
#include <hip/hip_runtime.h>
#include <hip/hip_bf16.h>

typedef __attribute__((ext_vector_type(8))) short bf16x8;
typedef __attribute__((ext_vector_type(4))) float f32x4;

constexpr int NB = 16, CIN = 256, COUT = 256, TDIM = 4096, KS = 3, PADV = 1;
constexpr int TT = 64;             // t per block
constexpr int NSTEP = 12;          // 4 c-blocks x 3 taps

typedef __attribute__((address_space(1))) const unsigned int gu32;
typedef __attribute__((address_space(3))) unsigned int lu32;

static __device__ __forceinline__ ushort f2bf(float f) {
    union { __hip_bfloat16 h; ushort u; } cv;
    cv.h = __float2bfloat16(f);
    return cv.u;
}
static __device__ __forceinline__ float bf2f(ushort u) {
    union { unsigned int u32; float f; } cv;
    cv.u32 = ((unsigned int)u) << 16;
    return cv.f;
}

// W pack for REGISTER A-frags: slot = (((s*2+ot)*4+wid)*2+kb)*2+mf, 1 KB each
// (64 lanes x 16B). Lane layout matches mfma A-frag: o = ot*128+wid*32+mf*16+
// (lane&15), kc-part = kb*32 + (lane>>4)*8 + e. Total 384 KB, L2-resident.
__global__ __launch_bounds__(256) void prepack_w2(const float* __restrict__ w,
                                                  __hip_bfloat16* __restrict__ wp2) {
    int idx = blockIdx.x * 256 + threadIdx.x;      // 196608
    if (idx >= NSTEP * COUT * 64) return;
    int e    = idx & 7;
    int lane = (idx >> 3) & 63;
    int mf   = (idx >> 9) & 1;
    int kb   = (idx >> 10) & 1;
    int wid  = (idx >> 11) & 3;
    int ot   = (idx >> 13) & 1;
    int s    = idx >> 14;                          // 0..11
    int o = ot * 128 + wid * 32 + mf * 16 + (lane & 15);
    int k = s % 3;
    int c = (s / 3) * 64 + kb * 32 + (lane >> 4) * 8 + e;
    wp2[idx] = __float2bfloat16(w[(o * CIN + c) * KS + k]);
}

// legacy pack for the fallback kernel (LDS image, pre-swizzled)
__global__ __launch_bounds__(256) void prepack_w(const float* __restrict__ w,
                                                 __hip_bfloat16* __restrict__ wp) {
    int idx = blockIdx.x * 256 + threadIdx.x;
    if (idx >= NSTEP * COUT * 64) return;
    int e  = idx & 7;
    int j  = (idx >> 3) & 7;
    int o  = (idx >> 6) & (COUT - 1);
    int s  = idx >> 14;
    int k  = s % 3;
    int c  = (s / 3) * 64 + ((j ^ (o & 7)) << 3) + e;
    wp[idx] = __float2bfloat16(w[(o * CIN + c) * KS + k]);
}

// x (B,C,T) f32  ->  xT (B,T,C) bf16.  64c x 64t tile per block via LDS.
__global__ __launch_bounds__(256) void transpose_x(const float* __restrict__ x,
                                                   ushort* __restrict__ xT) {
    __shared__ ushort tile[64][72];
    const int b  = blockIdx.z;
    const int c0 = blockIdx.y * 64;
    const int t0 = blockIdx.x * 64;
    const int tid = threadIdx.x;
    {
        const int c  = tid >> 2;
        const int tq = (tid & 3) << 4;
        const float* src = x + ((size_t)(b * CIN + c0 + c)) * TDIM + t0 + tq;
        #pragma unroll
        for (int i = 0; i < 4; ++i) {
            float4 f = *(const float4*)(src + 4 * i);
            tile[tq + 4 * i + 0][c] = f2bf(f.x);
            tile[tq + 4 * i + 1][c] = f2bf(f.y);
            tile[tq + 4 * i + 2][c] = f2bf(f.z);
            tile[tq + 4 * i + 3][c] = f2bf(f.w);
        }
    }
    __syncthreads();
    {
        const int t = tid >> 2;
        const int q = tid & 3;
        const uint4* lp = (const uint4*)&tile[t][q * 16];
        uint4 v0 = lp[0], v1 = lp[1];
        uint4* dst = (uint4*)(xT + ((size_t)b * TDIM + t0 + t) * CIN + c0 + q * 16);
        dst[0] = v0;
        dst[1] = v1;
    }
}

// ---- main kernel: 256 threads, 128o x 64t tile, W in registers from L2 ----
__global__ __launch_bounds__(256, 4) void deform_mfma_xt(
    const ushort* __restrict__ xT,            // (NB, TDIM, CIN) bf16
    const float* __restrict__ off,            // (NB, 2*KS, TDIM, 1)
    const ushort* __restrict__ wp2,           // reg-frag pack, 384 KB
    const float* __restrict__ bias,           // (COUT)
    float* __restrict__ out)                  // (NB, COUT, TDIM)
{
    __shared__ ushort v_s[TT * 64];         // 8 KB swizzled V tile [t][c]
    __shared__ int4   sP[KS][TT];           // {base, waf, wbf, -}  3 KB

    const int tid = threadIdx.x;

    // XCD swizzle: 2048 blocks; XCD q (= bid&7) owns batches {2q, 2q+1}.
    const int bid = blockIdx.x;            // 0..2047
    const int q   = bid & 7;
    const int r   = bid >> 3;              // 0..255
    const int b   = 2 * q + (r >> 7);
    const int r2  = r & 127;
    const int ot  = r2 >> 6;               // o half (0..1)
    const int tt0 = (r2 & 63) * TT;

    // ---- Phase A: per-(k,t) base row + pair-ordered f32 weights ----
    if (tid < KS * TT) {
        int k = tid >> 6, j = tid & (TT - 1);
        int t = tt0 + j;
        float dyr = off[((b * 2 * KS + 2 * k) * TDIM) + t];
        float dxr = off[((b * 2 * KS + 2 * k + 1) * TDIM) + t];
        float dyk = dyr - (float)(k - PADV);
        float py  = (float)(t - PADV + k) + dyk;
        float i0f = floorf(py);
        float fr  = py - i0f;
        int i0 = (int)i0f, i1 = i0 + 1;
        float wx = fmaxf(0.0f, 1.0f - fabsf(dxr));
        float w0 = (1.0f - fr) * wx * ((i0 >= 0 && i0 < TDIM) ? 1.0f : 0.0f);
        float w1 = fr * wx * ((i1 >= 0 && i1 < TDIM) ? 1.0f : 0.0f);
        int base = min(max(i0, 0), TDIM - 2);
        bool iA = (i0 == base);
        float wa = iA ? w0 : ((i0 + 1 == base) ? w1 : 0.0f);
        float wb = iA ? w1 : ((i0 == base + 1) ? w0 : 0.0f);
        int4 p;
        p.x = base;
        p.y = __float_as_int(wa);
        p.z = __float_as_int(wb);
        p.w = 0;
        sP[k][j] = p;
    }

    const int wid  = tid >> 6;             // 0..3 -> o sub-tile
    const int lane = tid & 63;
    const int lr   = lane & 15;
    const int lg   = lane >> 4;

    // V-phase mapping: 8 lanes per t -> coalesced 128B row segments
    const int tg   = tid >> 3;             // 0..31
    const int slot = tid & 7;
    const int t0l  = tg;
    const int t1l  = tg + 32;
    const int voffA = (t0l * 128 + slot * 16) ^ ((t0l & 7) << 4);
    const int voffB = (t1l * 128 + slot * 16) ^ ((t1l & 7) << 4);

    f32x4 acc[2][4];
    #pragma unroll
    for (int i = 0; i < 2; ++i)
        #pragma unroll
        for (int j = 0; j < 4; ++j) acc[i][j] = (f32x4)0.0f;

    const ushort* xTb = xT + (size_t)b * TDIM * CIN;

    for (int cb = 0; cb < 4; ++cb) {
      const int cbase = cb * 64;
      for (int k = 0; k < 3; ++k) {
        const int s_idx = cb * 3 + k;
        __syncthreads();   // MFMA(prev) done -> v_s writable; sP visible (s=0)

        // ---- W A-frags: 4 x b128 straight to regs (L2-resident pack) ----
        const ushort* wslot = wp2 + (size_t)(((s_idx * 2 + ot) * 4 + wid) * 4) * 512
                                  + lane * 8;
        bf16x8 af00 = *(const bf16x8*)(wslot);           // kb0 mf0
        bf16x8 af01 = *(const bf16x8*)(wslot + 512);     // kb0 mf1
        bf16x8 af10 = *(const bf16x8*)(wslot + 1024);    // kb1 mf0
        bf16x8 af11 = *(const bf16x8*)(wslot + 1536);    // kb1 mf1

        // ---- stage V: coalesced b128 gathers (all issued first) ----
        {
            int4 e0 = sP[k][t0l];
            int4 e1 = sP[k][t1l];
            const ushort* rowA = xTb + (size_t)e0.x * CIN + cbase + slot * 8;
            const ushort* rowB = xTb + (size_t)e1.x * CIN + cbase + slot * 8;
            bf16x8 a0 = *(const bf16x8*)rowA;
            bf16x8 a1 = *(const bf16x8*)(rowA + CIN);
            bf16x8 b0 = *(const bf16x8*)rowB;
            bf16x8 b1 = *(const bf16x8*)(rowB + CIN);
            float wa0 = __int_as_float(e0.y), wb0 = __int_as_float(e0.z);
            float wa1 = __int_as_float(e1.y), wb1 = __int_as_float(e1.z);
            bf16x8 pk0, pk1;
            #pragma unroll
            for (int i = 0; i < 8; ++i) {
                pk0[i] = (short)f2bf(bf2f((ushort)a0[i]) * wa0 + bf2f((ushort)a1[i]) * wb0);
                pk1[i] = (short)f2bf(bf2f((ushort)b0[i]) * wa1 + bf2f((ushort)b1[i]) * wb1);
            }
            *(bf16x8*)((char*)v_s + voffA) = pk0;
            *(bf16x8*)((char*)v_s + voffB) = pk1;
        }

        __syncthreads();   // v ready; af + gathers drained by barrier wait

        // ---- MFMA: wave computes 32(o) x 64(t), K=64 ----
        #pragma unroll
        for (int kb = 0; kb < 2; ++kb) {
            const int kk = kb * 32 + lg * 8;
            bf16x8 bfr[4];
            #pragma unroll
            for (int nf = 0; nf < 4; ++nf) {
                int tc = nf * 16 + lr;
                int byte = (tc * 128 + kk * 2) ^ ((tc & 7) << 4);
                bfr[nf] = *(const bf16x8*)((const char*)v_s + byte);
            }
            bf16x8 a0 = kb ? af10 : af00;
            bf16x8 a1 = kb ? af11 : af01;
            #pragma unroll
            for (int nf = 0; nf < 4; ++nf) {
                acc[0][nf] = __builtin_amdgcn_mfma_f32_16x16x32_bf16(a0, bfr[nf], acc[0][nf], 0, 0, 0);
                acc[1][nf] = __builtin_amdgcn_mfma_f32_16x16x32_bf16(a1, bfr[nf], acc[1][nf], 0, 0, 0);
            }
        }
      }
    }

    // ---- Epilogue: D col = lane&15 (t), row = (lane>>4)*4 + reg (o) ----
    #pragma unroll
    for (int mf = 0; mf < 2; ++mf) {
        #pragma unroll
        for (int rg = 0; rg < 4; ++rg) {
            int o = ot * 128 + wid * 32 + mf * 16 + lg * 4 + rg;
            float bv = bias[o];
            float* orow = out + (size_t)(b * COUT + o) * TDIM + tt0;
            #pragma unroll
            for (int nf = 0; nf < 4; ++nf)
                orow[nf * 16 + lr] = acc[mf][nf][rg] + bv;
        }
    }
}

// ---- fallback (proven R6 kernel, 128-t tile): scalar gathers from x ----
__global__ __launch_bounds__(512, 4) void deform_mfma_gather(
    const float* __restrict__ x,
    const float* __restrict__ off,
    const __hip_bfloat16* __restrict__ wp,
    const float* __restrict__ bias,
    float* __restrict__ out)
{
    __shared__ ushort w_s[COUT * 64];
    __shared__ ushort v_s[128 * 64];
    __shared__ int4   sP[KS][128];

    const int tid = threadIdx.x;
    const int bid  = blockIdx.x;
    const int q    = bid & 7;
    const int r    = bid >> 3;
    const int b    = 2 * q + (r >> 5);
    const int tt0  = (r & 31) * 128;

    if (tid < KS * 128) {
        int k = tid >> 7, j = tid & 127;
        int t = tt0 + j;
        float dyr = off[((b * 2 * KS + 2 * k) * TDIM) + t];
        float dxr = off[((b * 2 * KS + 2 * k + 1) * TDIM) + t];
        float py  = (float)(t - PADV + k) + dyr - (float)(k - PADV);
        float i0f = floorf(py);
        float fr  = py - i0f;
        int i0 = (int)i0f, i1 = i0 + 1;
        float wx = fmaxf(0.0f, 1.0f - fabsf(dxr));
        float w0 = (1.0f - fr) * wx * ((i0 >= 0 && i0 < TDIM) ? 1.0f : 0.0f);
        float w1 = fr * wx * ((i1 >= 0 && i1 < TDIM) ? 1.0f : 0.0f);
        int4 p;
        p.x = min(max(i0, 0), TDIM - 1);
        p.y = min(max(i1, 0), TDIM - 1);
        p.z = __float_as_int(w0);
        p.w = __float_as_int(w1);
        sP[k][j] = p;
    }

    const int wid    = tid >> 6;
    const int lane   = tid & 63;
    const int o_base = (wid >> 1) * 64;
    const int t_base = (wid & 1) * 64;
    const int lr     = lane & 15;
    const int lg     = lane >> 4;

    f32x4 acc[4][4];
    #pragma unroll
    for (int i = 0; i < 4; ++i)
        #pragma unroll
        for (int j = 0; j < 4; ++j) acc[i][j] = (f32x4)0.0f;

    const float* xb = x + (size_t)b * CIN * TDIM;

    for (int cb = 0; cb < 4; ++cb) {
      for (int k = 0; k < 3; ++k) {
        const int s_idx = cb * 3 + k;
        const int c0    = cb * 64;
        __syncthreads();
        {
            const char* gbase = (const char*)wp + (size_t)s_idx * 32768 + wid * 4096 + lane * 16;
            char* lbase = (char*)w_s + wid * 4096;
            #pragma unroll
            for (int i = 0; i < 4; ++i)
                __builtin_amdgcn_global_load_lds((gu32*)(gbase + i * 1024),
                                                 (lu32*)(lbase + i * 1024), 16, 0, 0);
        }
        {
            const int coct0 = tid >> 7;
            const int t     = tid & 127;
            int4 p = sP[k][t];
            const float* xr0 = xb + (size_t)(c0 + coct0 * 8) * TDIM;
            const float* xr1 = xr0 + (size_t)32 * TDIM;
            float g0[16], g1[16];
            #pragma unroll
            for (int i = 0; i < 8; ++i) {
                g0[2 * i]     = xr0[p.x];
                g0[2 * i + 1] = xr0[p.y];
                xr0 += TDIM;
            }
            #pragma unroll
            for (int i = 0; i < 8; ++i) {
                g1[2 * i]     = xr1[p.x];
                g1[2 * i + 1] = xr1[p.y];
                xr1 += TDIM;
            }
            float w0 = __int_as_float(p.z), w1 = __int_as_float(p.w);
            bf16x8 pk0, pk1;
            #pragma unroll
            for (int i = 0; i < 8; ++i) {
                pk0[i] = (short)f2bf(g0[2 * i] * w0 + g0[2 * i + 1] * w1);
                pk1[i] = (short)f2bf(g1[2 * i] * w0 + g1[2 * i + 1] * w1);
            }
            int row = t * 128;
            int swz = (t & 7) << 4;
            *(bf16x8*)((char*)v_s + ((row + coct0 * 16) ^ swz))       = pk0;
            *(bf16x8*)((char*)v_s + ((row + (coct0 + 4) * 16) ^ swz)) = pk1;
        }
        __syncthreads();
        #pragma unroll
        for (int kb = 0; kb < 2; ++kb) {
            const int kk = kb * 32 + lg * 8;
            bf16x8 bfr[4];
            #pragma unroll
            for (int nf = 0; nf < 4; ++nf) {
                int tc = t_base + nf * 16 + lr;
                int byte = (tc * 128 + kk * 2) ^ ((tc & 7) << 4);
                bfr[nf] = *(const bf16x8*)((const char*)v_s + byte);
            }
            #pragma unroll
            for (int mf = 0; mf < 4; ++mf) {
                int o  = o_base + mf * 16 + lr;
                int byte = (o * 128 + kk * 2) ^ ((o & 7) << 4);
                bf16x8 af = *(const bf16x8*)((const char*)w_s + byte);
                #pragma unroll
                for (int nf = 0; nf < 4; ++nf)
                    acc[mf][nf] = __builtin_amdgcn_mfma_f32_16x16x32_bf16(
                        af, bfr[nf], acc[mf][nf], 0, 0, 0);
            }
        }
      }
    }

    #pragma unroll
    for (int mf = 0; mf < 4; ++mf) {
        #pragma unroll
        for (int rg = 0; rg < 4; ++rg) {
            int o = o_base + mf * 16 + lg * 4 + rg;
            float bv = bias[o];
            float* orow = out + (size_t)(b * COUT + o) * TDIM + tt0 + t_base;
            #pragma unroll
            for (int nf = 0; nf < 4; ++nf)
                orow[nf * 16 + lr] = acc[mf][nf][rg] + bv;
        }
    }
}

extern "C" void kernel_launch(void* const* d_in, const int* in_sizes, int n_in,
                              void* d_out, int out_size, void* d_ws, size_t ws_size,
                              hipStream_t stream) {
    const float* x    = (const float*)d_in[0];
    const float* off  = (const float*)d_in[1];
    const float* w    = (const float*)d_in[2];
    const float* bias = (const float*)d_in[3];
    float* out = (float*)d_out;

    const size_t xt_off  = 512 * 1024;
    const size_t xt_need = xt_off + (size_t)NB * TDIM * CIN * sizeof(ushort);

    if (ws_size >= xt_need) {
        ushort* wp2 = (ushort*)d_ws;                       // 384 KB reg-frag pack
        ushort* xT  = (ushort*)((char*)d_ws + xt_off);     // 32 MB
        prepack_w2<<<dim3(768), dim3(256), 0, stream>>>(w, (__hip_bfloat16*)wp2);
        transpose_x<<<dim3(TDIM / 64, CIN / 64, NB), dim3(256), 0, stream>>>(x, xT);
        deform_mfma_xt<<<dim3(2048), dim3(256), 0, stream>>>(xT, off, wp2, bias, out);
    } else {
        __hip_bfloat16* wp = (__hip_bfloat16*)d_ws;        // 384 KB LDS-image pack
        prepack_w<<<dim3(768), dim3(256), 0, stream>>>(w, wp);
        deform_mfma_gather<<<dim3(512), dim3(512), 0, stream>>>(x, off, wp, bias, out);
    }
}